// Round 1
// baseline (3186.397 us; speedup 1.0000x reference)
//
#include <hip/hip_runtime.h>

#define B_SZ   256
#define NCAP   128
#define D_INP  768
#define NO     4096      // NC * D_CAP
#define K_FLAT 98304     // NC * D_IN
#define PADD   36        // padded row stride (floats) for [128][32] LDS tiles

// ---------------------------------------------------------------------------
// GEMM1 (split-K, atomic): a1[b,c] += x_flat[b,:] . l1_w[c,:]
// tile 64(b) x 64(c), k-chunk 1024 (32 slabs of 32), grid (2,4,96)
// ---------------------------------------------------------------------------
__global__ __launch_bounds__(256) void gemm1_kernel(
    const float* __restrict__ x,    // [256, 98304]
    const float* __restrict__ l1w,  // [128, 98304]
    float* __restrict__ a1)         // [256, 128] (zeroed)
{
    __shared__ float As[32][68];  // [k][row], 68 keeps rows 16B-aligned
    __shared__ float Bs[32][68];  // [k][col]
    const int t = threadIdx.x;
    const int col0 = blockIdx.x * 64;
    const int row0 = blockIdx.y * 64;
    const int kch0 = blockIdx.z * 1024;
    const int tx = t & 15, ty = t >> 4;
    float acc[4][4] = {};
    for (int slab = 0; slab < 32; ++slab) {
        const int kb = kch0 + slab * 32;
        __syncthreads();
        #pragma unroll
        for (int id = t; id < 512; id += 256) {
            const int r = id >> 3, kq = (id & 7) * 4;
            const float4 av = *(const float4*)&x[(size_t)(row0 + r) * K_FLAT + kb + kq];
            As[kq + 0][r] = av.x; As[kq + 1][r] = av.y; As[kq + 2][r] = av.z; As[kq + 3][r] = av.w;
            const float4 bv = *(const float4*)&l1w[(size_t)(col0 + r) * K_FLAT + kb + kq];
            Bs[kq + 0][r] = bv.x; Bs[kq + 1][r] = bv.y; Bs[kq + 2][r] = bv.z; Bs[kq + 3][r] = bv.w;
        }
        __syncthreads();
        #pragma unroll
        for (int k = 0; k < 32; ++k) {
            const float4 a4 = *(const float4*)&As[k][ty * 4];
            const float4 b4 = *(const float4*)&Bs[k][tx * 4];
            const float a[4] = {a4.x, a4.y, a4.z, a4.w};
            const float b[4] = {b4.x, b4.y, b4.z, b4.w};
            #pragma unroll
            for (int i = 0; i < 4; ++i)
                #pragma unroll
                for (int j = 0; j < 4; ++j) acc[i][j] += a[i] * b[j];
        }
    }
    #pragma unroll
    for (int i = 0; i < 4; ++i)
        #pragma unroll
        for (int j = 0; j < 4; ++j)
            atomicAdd(&a1[(row0 + ty * 4 + i) * NCAP + col0 + tx * 4 + j], acc[i][j]);
}

// ---------------------------------------------------------------------------
// att: in-place  a1[b,:] -> g[b,:] = 1 + tanh(relu(a1+l1_b) @ l2_w.T + l2_b)
// ---------------------------------------------------------------------------
__global__ __launch_bounds__(128) void att_kernel(
    float* __restrict__ buf,        // [256,128]: in a1, out gate
    const float* __restrict__ l1b,  // [128]
    const float* __restrict__ l2w,  // [128,128]
    const float* __restrict__ l2b)  // [128]
{
    __shared__ float sa[NCAP];
    const int b = blockIdx.x, t = threadIdx.x;
    const float v = buf[b * NCAP + t] + l1b[t];
    sa[t] = v > 0.f ? v : 0.f;
    __syncthreads();
    float s = l2b[t];
    #pragma unroll 4
    for (int c = 0; c < NCAP; ++c) s += sa[c] * l2w[t * NCAP + c];
    buf[b * NCAP + t] = 1.f + tanhf(s);
}

// ---------------------------------------------------------------------------
// GEMM2: p[row,o] = g[row] * (x[row,:] . W[o,:]) + bias[row%128, o]
// tile 128x128, microtile 8x8 (split 4+4), kc=16. grid (32 otiles, 256 b)
// ---------------------------------------------------------------------------
__global__ __launch_bounds__(256) void gemm2_kernel(
    const float* __restrict__ x,     // [32768, 768]
    const float* __restrict__ W,     // [4096, 768]
    const float* __restrict__ bias,  // [128, 4096]
    const float* __restrict__ g,     // [32768]
    float* __restrict__ p)           // [32768, 4096]
{
    __shared__ float As[16][132];   // [k][row]
    __shared__ float Bs[16][132];   // [k][col]
    __shared__ float sg[NCAP];
    const int t = threadIdx.x;
    const int col0 = blockIdx.x * 128;
    const int b    = blockIdx.y;
    const int row0 = b * NCAP;
    const int tx = t & 15, ty = t >> 4;
    if (t < 128) sg[t] = g[row0 + t];
    float acc[2][2][4][4] = {};
    for (int ks = 0; ks < D_INP; ks += 16) {
        __syncthreads();
        #pragma unroll
        for (int id = t; id < 512; id += 256) {
            const int r = id >> 2, kq = (id & 3) * 4;
            const float4 av = *(const float4*)&x[(size_t)(row0 + r) * D_INP + ks + kq];
            As[kq + 0][r] = av.x; As[kq + 1][r] = av.y; As[kq + 2][r] = av.z; As[kq + 3][r] = av.w;
            const float4 bv = *(const float4*)&W[(size_t)(col0 + r) * D_INP + ks + kq];
            Bs[kq + 0][r] = bv.x; Bs[kq + 1][r] = bv.y; Bs[kq + 2][r] = bv.z; Bs[kq + 3][r] = bv.w;
        }
        __syncthreads();
        #pragma unroll
        for (int k = 0; k < 16; ++k) {
            const float4 a0 = *(const float4*)&As[k][ty * 4];
            const float4 a1 = *(const float4*)&As[k][64 + ty * 4];
            const float4 b0 = *(const float4*)&Bs[k][tx * 4];
            const float4 b1 = *(const float4*)&Bs[k][64 + tx * 4];
            const float ar[2][4] = {{a0.x, a0.y, a0.z, a0.w}, {a1.x, a1.y, a1.z, a1.w}};
            const float br[2][4] = {{b0.x, b0.y, b0.z, b0.w}, {b1.x, b1.y, b1.z, b1.w}};
            #pragma unroll
            for (int rh = 0; rh < 2; ++rh)
                #pragma unroll
                for (int i = 0; i < 4; ++i)
                    #pragma unroll
                    for (int ch = 0; ch < 2; ++ch)
                        #pragma unroll
                        for (int j = 0; j < 4; ++j)
                            acc[rh][ch][i][j] += ar[rh][i] * br[ch][j];
        }
    }
    #pragma unroll
    for (int rh = 0; rh < 2; ++rh)
        #pragma unroll
        for (int i = 0; i < 4; ++i) {
            const int r = rh * 64 + ty * 4 + i;      // local row == n
            const float gv = sg[r];
            const size_t prow = (size_t)(row0 + r) * NO + col0;
            const size_t brow = (size_t)r * NO + col0;
            #pragma unroll
            for (int ch = 0; ch < 2; ++ch) {
                const int c = ch * 64 + tx * 4;
                const float4 bv = *(const float4*)&bias[brow + c];
                float4 o;
                o.x = acc[rh][ch][i][0] * gv + bv.x;
                o.y = acc[rh][ch][i][1] * gv + bv.y;
                o.z = acc[rh][ch][i][2] * gv + bv.z;
                o.w = acc[rh][ch][i][3] * gv + bv.w;
                *(float4*)&p[prow + c] = o;
            }
        }
}

// ---------------------------------------------------------------------------
// Routing: one block per batch element, 512 threads.
// s1(uniform) -> cc1 -> [pass0: b=dot(p,cc1); beta; s2] -> cc2
//             -> [pass1: b+=dot(p,cc2); beta; s3] -> out = ||squash(s3)||
// ---------------------------------------------------------------------------
__global__ __launch_bounds__(512) void routing_kernel(
    const float* __restrict__ p,   // [256,128,128,32]
    float* __restrict__ out)       // [256,128]
{
    __shared__ float bl[NCAP * NCAP];     // 64 KB  b-logits [i][j]
    __shared__ float ps[NCAP * PADD];     // 18 KB  current p row [j][d] / s buffer
    __shared__ float cc[NCAP * PADD];     // 18 KB  cc [j][d]
    __shared__ float red[NCAP];
    __shared__ float rtmp[2];
    const int t = threadIdx.x;
    const int b = blockIdx.x;
    const float* pb = p + (size_t)b * (NCAP * NCAP * 32);

    const int wj = t >> 3;                 // 0..63: write row for staging
    const int wd = 4 * (t & 7);            // 0,4,...,28

    // ---- Phase A: s1 = (1/128) sum_i p[i,:,:]
    {
        float4 a0 = {0, 0, 0, 0}, a1 = {0, 0, 0, 0};
        for (int i = 0; i < NCAP; ++i) {
            const float4 v0 = *(const float4*)&pb[(size_t)i * NO + 4 * t];
            const float4 v1 = *(const float4*)&pb[(size_t)i * NO + 2048 + 4 * t];
            a0.x += v0.x; a0.y += v0.y; a0.z += v0.z; a0.w += v0.w;
            a1.x += v1.x; a1.y += v1.y; a1.z += v1.z; a1.w += v1.w;
        }
        const float inv = 1.f / 128.f;
        a0.x *= inv; a0.y *= inv; a0.z *= inv; a0.w *= inv;
        a1.x *= inv; a1.y *= inv; a1.z *= inv; a1.w *= inv;
        *(float4*)&ps[wj * PADD + wd] = a0;
        *(float4*)&ps[(64 + wj) * PADD + wd] = a1;
    }
    __syncthreads();
    if (t < NCAP) {  // squash ps -> cc
        float n2 = 0.f;
        #pragma unroll
        for (int d = 0; d < 32; ++d) { const float v = ps[t * PADD + d]; n2 += v * v; }
        const float f = sqrtf(n2) / (0.5f + n2);
        #pragma unroll
        for (int d = 0; d < 32; ++d) cc[t * PADD + d] = ps[t * PADD + d] * f;
    }
    __syncthreads();

    for (int pass = 0; pass < 2; ++pass) {
        float4 r0 = *(const float4*)&pb[4 * t];
        float4 r1 = *(const float4*)&pb[2048 + 4 * t];
        float sacc[8] = {0, 0, 0, 0, 0, 0, 0, 0};
        for (int i = 0; i < NCAP; ++i) {
            __syncthreads();  // (1) ps free from previous iteration
            *(float4*)&ps[wj * PADD + wd] = r0;
            *(float4*)&ps[(64 + wj) * PADD + wd] = r1;
            if (i < NCAP - 1) {
                r0 = *(const float4*)&pb[(size_t)(i + 1) * NO + 4 * t];
                r1 = *(const float4*)&pb[(size_t)(i + 1) * NO + 2048 + 4 * t];
            }
            __syncthreads();  // (2) ps ready
            // dot(p[i,j,:], cc[j,:]) with 4 lanes per j
            const int jj = t >> 2, pp = t & 3;
            const int base = jj * PADD + pp * 8;
            const float4 p0 = *(const float4*)&ps[base];
            const float4 p1 = *(const float4*)&ps[base + 4];
            const float4 c0 = *(const float4*)&cc[base];
            const float4 c1 = *(const float4*)&cc[base + 4];
            float dp = p0.x * c0.x + p0.y * c0.y + p0.z * c0.z + p0.w * c0.w
                     + p1.x * c1.x + p1.y * c1.y + p1.z * c1.z + p1.w * c1.w;
            dp += __shfl_xor(dp, 1);
            dp += __shfl_xor(dp, 2);
            if (pp == 0) {
                const float bnew = pass ? (bl[i * NCAP + jj] + dp) : dp;
                bl[i * NCAP + jj] = bnew;
                red[jj] = bnew;
            }
            __syncthreads();  // (3) logits ready
            float e = 0.f;
            if (t < NCAP) {
                e = __expf(red[t]);   // logits bounded (~|17|) -> no max-sub needed
                float sm = e;
                #pragma unroll
                for (int off = 32; off >= 1; off >>= 1) sm += __shfl_xor(sm, off);
                if ((t & 63) == 0) rtmp[t >> 6] = sm;
            }
            __syncthreads();  // (4) wave partial sums ready
            if (t < NCAP) red[t] = e / (rtmp[0] + rtmp[1]);  // beta
            __syncthreads();  // (5) beta ready
            #pragma unroll
            for (int q = 0; q < 8; ++q) {
                const int f = t + 512 * q;
                sacc[q] += red[f >> 5] * ps[(f >> 5) * PADD + (f & 31)];
            }
        }
        __syncthreads();
        #pragma unroll
        for (int q = 0; q < 8; ++q) {
            const int f = t + 512 * q;
            ps[(f >> 5) * PADD + (f & 31)] = sacc[q];   // ps := s
        }
        __syncthreads();
        if (pass == 0) {
            if (t < NCAP) {  // squash s2 -> cc
                float n2 = 0.f;
                #pragma unroll
                for (int d = 0; d < 32; ++d) { const float v = ps[t * PADD + d]; n2 += v * v; }
                const float f = sqrtf(n2) / (0.5f + n2);
                #pragma unroll
                for (int d = 0; d < 32; ++d) cc[t * PADD + d] = ps[t * PADD + d] * f;
            }
            __syncthreads();
        } else {
            if (t < NCAP) {  // out = clip(||squash(s3)||) = n2/(0.5+n2)
                float n2 = 0.f;
                #pragma unroll
                for (int d = 0; d < 32; ++d) { const float v = ps[t * PADD + d]; n2 += v * v; }
                float val = n2 / (0.5f + n2);
                val = fminf(fmaxf(val, 1e-6f), 1.f - 1e-6f);
                out[b * NCAP + t] = val;
            }
        }
    }
}

// ---------------------------------------------------------------------------
extern "C" void kernel_launch(void* const* d_in, const int* in_sizes, int n_in,
                              void* d_out, int out_size, void* d_ws, size_t ws_size,
                              hipStream_t stream) {
    const float* x    = (const float*)d_in[0];
    const float* W    = (const float*)d_in[1];
    const float* bias = (const float*)d_in[2];
    const float* l1w  = (const float*)d_in[3];
    const float* l1b  = (const float*)d_in[4];
    const float* l2w  = (const float*)d_in[5];
    const float* l2b  = (const float*)d_in[6];
    float* out = (float*)d_out;            // [256,128]; doubles as a1/gate scratch
    float* p   = out + B_SZ * NCAP;        // [256,128,128,32]

    hipMemsetAsync(out, 0, B_SZ * NCAP * sizeof(float), stream);
    gemm1_kernel<<<dim3(2, 4, 96), 256, 0, stream>>>(x, l1w, out);
    att_kernel<<<dim3(B_SZ), 128, 0, stream>>>(out, l1b, l2w, l2b);
    gemm2_kernel<<<dim3(32, B_SZ), 256, 0, stream>>>(x, W, bias, out, p);
    routing_kernel<<<dim3(B_SZ), 512, 0, stream>>>(p, out);
}

// Round 3
// 1452.355 us; speedup vs baseline: 2.1940x; 2.1940x over previous
//
#include <hip/hip_runtime.h>

#define B_SZ   256
#define NCAP   128
#define D_INP  768
#define NO     4096      // NC * D_CAP
#define K_FLAT 98304     // NC * D_IN
#define PADD   36        // padded row stride (floats) for [128][32] LDS tiles

typedef _Float16 half8 __attribute__((ext_vector_type(8)));
typedef float f32x4 __attribute__((ext_vector_type(4)));

// global->LDS direct DMA, 16B per lane. LDS dest must be linear (wave base + lane*16).
#define GLOAD16(gp, lp) \
    __builtin_amdgcn_global_load_lds((const __attribute__((address_space(1))) void*)(gp), \
                                     (__attribute__((address_space(3))) void*)(lp), 16, 0, 0)

// ---------------------------------------------------------------------------
// GEMM1 (split-K, atomic): a1[b,c] += x_flat[b,:] . l1_w[c,:]   (f32, mem-bound)
// ---------------------------------------------------------------------------
__global__ __launch_bounds__(256) void gemm1_kernel(
    const float* __restrict__ x,    // [256, 98304]
    const float* __restrict__ l1w,  // [128, 98304]
    float* __restrict__ a1)         // [256, 128] (zeroed)
{
    __shared__ float As[32][68];
    __shared__ float Bs[32][68];
    const int t = threadIdx.x;
    const int col0 = blockIdx.x * 64;
    const int row0 = blockIdx.y * 64;
    const int kch0 = blockIdx.z * 1024;
    const int tx = t & 15, ty = t >> 4;
    float acc[4][4] = {};
    for (int slab = 0; slab < 32; ++slab) {
        const int kb = kch0 + slab * 32;
        __syncthreads();
        #pragma unroll
        for (int id = t; id < 512; id += 256) {
            const int r = id >> 3, kq = (id & 7) * 4;
            const float4 av = *(const float4*)&x[(size_t)(row0 + r) * K_FLAT + kb + kq];
            As[kq + 0][r] = av.x; As[kq + 1][r] = av.y; As[kq + 2][r] = av.z; As[kq + 3][r] = av.w;
            const float4 bv = *(const float4*)&l1w[(size_t)(col0 + r) * K_FLAT + kb + kq];
            Bs[kq + 0][r] = bv.x; Bs[kq + 1][r] = bv.y; Bs[kq + 2][r] = bv.z; Bs[kq + 3][r] = bv.w;
        }
        __syncthreads();
        #pragma unroll
        for (int k = 0; k < 32; ++k) {
            const float4 a4 = *(const float4*)&As[k][ty * 4];
            const float4 b4 = *(const float4*)&Bs[k][tx * 4];
            const float a[4] = {a4.x, a4.y, a4.z, a4.w};
            const float b[4] = {b4.x, b4.y, b4.z, b4.w};
            #pragma unroll
            for (int i = 0; i < 4; ++i)
                #pragma unroll
                for (int j = 0; j < 4; ++j) acc[i][j] += a[i] * b[j];
        }
    }
    #pragma unroll
    for (int i = 0; i < 4; ++i)
        #pragma unroll
        for (int j = 0; j < 4; ++j)
            atomicAdd(&a1[(row0 + ty * 4 + i) * NCAP + col0 + tx * 4 + j], acc[i][j]);
}

// ---------------------------------------------------------------------------
// att: in-place  a1[b,:] -> g[b,:] = 1 + tanh(relu(a1+l1_b) @ l2_w.T + l2_b)
// ---------------------------------------------------------------------------
__global__ __launch_bounds__(128) void att_kernel(
    float* __restrict__ buf,
    const float* __restrict__ l1b,
    const float* __restrict__ l2w,
    const float* __restrict__ l2b)
{
    __shared__ float sa[NCAP];
    const int b = blockIdx.x, t = threadIdx.x;
    const float v = buf[b * NCAP + t] + l1b[t];
    sa[t] = v > 0.f ? v : 0.f;
    __syncthreads();
    float s = l2b[t];
    #pragma unroll 4
    for (int c = 0; c < NCAP; ++c) s += sa[c] * l2w[t * NCAP + c];
    buf[b * NCAP + t] = 1.f + tanhf(s);
}

// ---------------------------------------------------------------------------
// convert: f32 [ntiles*128, 768] -> fp16 in MFMA-fragment-order blocks:
// dst[(tile*24+kt)*4096 + kg*1024 + r*8 + e] = src[tile*128+r][kt*32+kg*8+e]
// so that linear global_load_lds staging of one 8KB chunk gives LDS layout
// [kg][row][8] -> ds_read_b128 fragment reads are conflict-free.
// ---------------------------------------------------------------------------
__global__ __launch_bounds__(256) void convert_kernel(
    const float* __restrict__ src, _Float16* __restrict__ dst)
{
    const int tid = blockIdx.x * 256 + threadIdx.x;  // (tile,kt,r,kg)
    const int kg = tid & 3;
    const int r  = (tid >> 2) & 127;
    const int rem = tid >> 9;            // tile*24 + kt
    const int kt = rem % 24;
    const int tile = rem / 24;
    const float* s = src + (size_t)(tile * 128 + r) * D_INP + kt * 32 + kg * 8;
    const float4 v0 = *(const float4*)s;
    const float4 v1 = *(const float4*)(s + 4);
    half8 h;
    h[0] = (_Float16)v0.x; h[1] = (_Float16)v0.y; h[2] = (_Float16)v0.z; h[3] = (_Float16)v0.w;
    h[4] = (_Float16)v1.x; h[5] = (_Float16)v1.y; h[6] = (_Float16)v1.z; h[7] = (_Float16)v1.w;
    *(half8*)(dst + (size_t)rem * 4096 + kg * 1024 + r * 8) = h;
}

// ---------------------------------------------------------------------------
// GEMM2 via fp16 MFMA: p[row,o] = g[row]*(x[row,:].W[o,:]) + bias[row%128,o]
// 128x128 tile, 4 waves (2x2), BK=32, mfma_f32_16x16x32_f16, m97 structure.
// ---------------------------------------------------------------------------
__global__ __launch_bounds__(256, 3) void gemm2_mfma(
    const _Float16* __restrict__ xh,   // [256][24][4096] fragment-order
    const _Float16* __restrict__ wh,   // [32][24][4096]  fragment-order
    const float* __restrict__ bias,    // [128, 4096]
    const float* __restrict__ g,       // [32768]
    float* __restrict__ p)             // [32768, 4096]
{
    __shared__ _Float16 As[4096];      // 8 KB: [kg(4)][row(128)][8]
    __shared__ _Float16 Bs[4096];      // 8 KB: [kg(4)][col(128)][8]
    __shared__ float sg[NCAP];
    const int t = threadIdx.x;
    const int w = t >> 6, l = t & 63;
    const int ct = blockIdx.x;         // col tile 0..31
    const int bt = blockIdx.y;         // row tile (batch n-block) 0..255
    const int wr = w >> 1, wc = w & 1;
    if (t < NCAP) sg[t] = g[bt * NCAP + t];
    const _Float16* ax = xh + (size_t)bt * (24 * 4096);
    const _Float16* bx = wh + (size_t)ct * (24 * 4096);
    f32x4 acc[4][4] = {};
    const int au = (l >> 4) * 128 + wr * 64 + (l & 15);  // in 8-elem units
    const int bu = (l >> 4) * 128 + wc * 64 + (l & 15);
    for (int kt = 0; kt < 24; ++kt) {
        __syncthreads();               // LDS free (also publishes sg at kt=0)
        const _Float16* ga = ax + kt * 4096 + t * 8;
        const _Float16* gb = bx + kt * 4096 + t * 8;
        GLOAD16(ga,        &As[t * 8]);
        GLOAD16(ga + 2048, &As[t * 8 + 2048]);
        GLOAD16(gb,        &Bs[t * 8]);
        GLOAD16(gb + 2048, &Bs[t * 8 + 2048]);
        __syncthreads();               // compiler drains vmcnt before barrier
        half8 a[4], b[4];
        #pragma unroll
        for (int m = 0; m < 4; ++m) a[m] = *(const half8*)&As[(au + m * 16) * 8];
        #pragma unroll
        for (int n = 0; n < 4; ++n) b[n] = *(const half8*)&Bs[(bu + n * 16) * 8];
        #pragma unroll
        for (int m = 0; m < 4; ++m)
            #pragma unroll
            for (int n = 0; n < 4; ++n)
                acc[m][n] = __builtin_amdgcn_mfma_f32_16x16x32_f16(a[m], b[n], acc[m][n], 0, 0, 0);
    }
    // epilogue: C/D layout col=l&15, row=(l>>4)*4+j
    const int colb = ct * 128 + wc * 64 + (l & 15);
    #pragma unroll
    for (int m = 0; m < 4; ++m) {
        const int rl0 = wr * 64 + m * 16 + (l >> 4) * 4;   // local row (== capsule n)
        #pragma unroll
        for (int j = 0; j < 4; ++j) {
            const int rl = rl0 + j;
            const float gv = sg[rl];
            const size_t prow = ((size_t)bt * NCAP + rl) * NO;
            const size_t brow = (size_t)rl * NO;
            #pragma unroll
            for (int n = 0; n < 4; ++n) {
                const int c = colb + n * 16;
                p[prow + c] = acc[m][n][j] * gv + bias[brow + c];
            }
        }
    }
}

// ---------------------------------------------------------------------------
// GEMM2 fallback (f32 vector) — used only if ws too small for fp16 copies.
// ---------------------------------------------------------------------------
__global__ __launch_bounds__(256) void gemm2_kernel(
    const float* __restrict__ x, const float* __restrict__ W,
    const float* __restrict__ bias, const float* __restrict__ g,
    float* __restrict__ p)
{
    __shared__ float As[16][132];
    __shared__ float Bs[16][132];
    __shared__ float sg[NCAP];
    const int t = threadIdx.x;
    const int col0 = blockIdx.x * 128;
    const int b    = blockIdx.y;
    const int row0 = b * NCAP;
    const int tx = t & 15, ty = t >> 4;
    if (t < 128) sg[t] = g[row0 + t];
    float acc[2][2][4][4] = {};
    for (int ks = 0; ks < D_INP; ks += 16) {
        __syncthreads();
        #pragma unroll
        for (int id = t; id < 512; id += 256) {
            const int r = id >> 2, kq = (id & 3) * 4;
            const float4 av = *(const float4*)&x[(size_t)(row0 + r) * D_INP + ks + kq];
            As[kq + 0][r] = av.x; As[kq + 1][r] = av.y; As[kq + 2][r] = av.z; As[kq + 3][r] = av.w;
            const float4 bv = *(const float4*)&W[(size_t)(col0 + r) * D_INP + ks + kq];
            Bs[kq + 0][r] = bv.x; Bs[kq + 1][r] = bv.y; Bs[kq + 2][r] = bv.z; Bs[kq + 3][r] = bv.w;
        }
        __syncthreads();
        #pragma unroll
        for (int k = 0; k < 16; ++k) {
            const float4 a0 = *(const float4*)&As[k][ty * 4];
            const float4 a1 = *(const float4*)&As[k][64 + ty * 4];
            const float4 b0 = *(const float4*)&Bs[k][tx * 4];
            const float4 b1 = *(const float4*)&Bs[k][64 + tx * 4];
            const float ar[2][4] = {{a0.x, a0.y, a0.z, a0.w}, {a1.x, a1.y, a1.z, a1.w}};
            const float br[2][4] = {{b0.x, b0.y, b0.z, b0.w}, {b1.x, b1.y, b1.z, b1.w}};
            #pragma unroll
            for (int rh = 0; rh < 2; ++rh)
                #pragma unroll
                for (int i = 0; i < 4; ++i)
                    #pragma unroll
                    for (int ch = 0; ch < 2; ++ch)
                        #pragma unroll
                        for (int j = 0; j < 4; ++j)
                            acc[rh][ch][i][j] += ar[rh][i] * br[ch][j];
        }
    }
    #pragma unroll
    for (int rh = 0; rh < 2; ++rh)
        #pragma unroll
        for (int i = 0; i < 4; ++i) {
            const int r = rh * 64 + ty * 4 + i;
            const float gv = sg[r];
            const size_t prow = (size_t)(row0 + r) * NO + col0;
            const size_t brow = (size_t)r * NO + col0;
            #pragma unroll
            for (int ch = 0; ch < 2; ++ch) {
                const int c = ch * 64 + tx * 4;
                const float4 bv = *(const float4*)&bias[brow + c];
                float4 o;
                o.x = acc[rh][ch][i][0] * gv + bv.x;
                o.y = acc[rh][ch][i][1] * gv + bv.y;
                o.z = acc[rh][ch][i][2] * gv + bv.z;
                o.w = acc[rh][ch][i][3] * gv + bv.w;
                *(float4*)&p[prow + c] = o;
            }
        }
}

// ---------------------------------------------------------------------------
// Routing: one block per batch element, 512 threads. (unchanged)
// ---------------------------------------------------------------------------
__global__ __launch_bounds__(512) void routing_kernel(
    const float* __restrict__ p,   // [256,128,128,32]
    float* __restrict__ out)       // [256,128]
{
    __shared__ float bl[NCAP * NCAP];
    __shared__ float ps[NCAP * PADD];
    __shared__ float cc[NCAP * PADD];
    __shared__ float red[NCAP];
    __shared__ float rtmp[2];
    const int t = threadIdx.x;
    const int b = blockIdx.x;
    const float* pb = p + (size_t)b * (NCAP * NCAP * 32);

    const int wj = t >> 3;
    const int wd = 4 * (t & 7);

    {
        float4 a0 = {0, 0, 0, 0}, a1 = {0, 0, 0, 0};
        for (int i = 0; i < NCAP; ++i) {
            const float4 v0 = *(const float4*)&pb[(size_t)i * NO + 4 * t];
            const float4 v1 = *(const float4*)&pb[(size_t)i * NO + 2048 + 4 * t];
            a0.x += v0.x; a0.y += v0.y; a0.z += v0.z; a0.w += v0.w;
            a1.x += v1.x; a1.y += v1.y; a1.z += v1.z; a1.w += v1.w;
        }
        const float inv = 1.f / 128.f;
        a0.x *= inv; a0.y *= inv; a0.z *= inv; a0.w *= inv;
        a1.x *= inv; a1.y *= inv; a1.z *= inv; a1.w *= inv;
        *(float4*)&ps[wj * PADD + wd] = a0;
        *(float4*)&ps[(64 + wj) * PADD + wd] = a1;
    }
    __syncthreads();
    if (t < NCAP) {
        float n2 = 0.f;
        #pragma unroll
        for (int d = 0; d < 32; ++d) { const float v = ps[t * PADD + d]; n2 += v * v; }
        const float f = sqrtf(n2) / (0.5f + n2);
        #pragma unroll
        for (int d = 0; d < 32; ++d) cc[t * PADD + d] = ps[t * PADD + d] * f;
    }
    __syncthreads();

    for (int pass = 0; pass < 2; ++pass) {
        float4 r0 = *(const float4*)&pb[4 * t];
        float4 r1 = *(const float4*)&pb[2048 + 4 * t];
        float sacc[8] = {0, 0, 0, 0, 0, 0, 0, 0};
        for (int i = 0; i < NCAP; ++i) {
            __syncthreads();
            *(float4*)&ps[wj * PADD + wd] = r0;
            *(float4*)&ps[(64 + wj) * PADD + wd] = r1;
            if (i < NCAP - 1) {
                r0 = *(const float4*)&pb[(size_t)(i + 1) * NO + 4 * t];
                r1 = *(const float4*)&pb[(size_t)(i + 1) * NO + 2048 + 4 * t];
            }
            __syncthreads();
            const int jj = t >> 2, pp = t & 3;
            const int base = jj * PADD + pp * 8;
            const float4 p0 = *(const float4*)&ps[base];
            const float4 p1 = *(const float4*)&ps[base + 4];
            const float4 c0 = *(const float4*)&cc[base];
            const float4 c1 = *(const float4*)&cc[base + 4];
            float dp = p0.x * c0.x + p0.y * c0.y + p0.z * c0.z + p0.w * c0.w
                     + p1.x * c1.x + p1.y * c1.y + p1.z * c1.z + p1.w * c1.w;
            dp += __shfl_xor(dp, 1);
            dp += __shfl_xor(dp, 2);
            if (pp == 0) {
                const float bnew = pass ? (bl[i * NCAP + jj] + dp) : dp;
                bl[i * NCAP + jj] = bnew;
                red[jj] = bnew;
            }
            __syncthreads();
            float e = 0.f;
            if (t < NCAP) {
                e = __expf(red[t]);
                float sm = e;
                #pragma unroll
                for (int off = 32; off >= 1; off >>= 1) sm += __shfl_xor(sm, off);
                if ((t & 63) == 0) rtmp[t >> 6] = sm;
            }
            __syncthreads();
            if (t < NCAP) red[t] = e / (rtmp[0] + rtmp[1]);
            __syncthreads();
            #pragma unroll
            for (int q = 0; q < 8; ++q) {
                const int f = t + 512 * q;
                sacc[q] += red[f >> 5] * ps[(f >> 5) * PADD + (f & 31)];
            }
        }
        __syncthreads();
        #pragma unroll
        for (int q = 0; q < 8; ++q) {
            const int f = t + 512 * q;
            ps[(f >> 5) * PADD + (f & 31)] = sacc[q];
        }
        __syncthreads();
        if (pass == 0) {
            if (t < NCAP) {
                float n2 = 0.f;
                #pragma unroll
                for (int d = 0; d < 32; ++d) { const float v = ps[t * PADD + d]; n2 += v * v; }
                const float f = sqrtf(n2) / (0.5f + n2);
                #pragma unroll
                for (int d = 0; d < 32; ++d) cc[t * PADD + d] = ps[t * PADD + d] * f;
            }
            __syncthreads();
        } else {
            if (t < NCAP) {
                float n2 = 0.f;
                #pragma unroll
                for (int d = 0; d < 32; ++d) { const float v = ps[t * PADD + d]; n2 += v * v; }
                float val = n2 / (0.5f + n2);
                val = fminf(fmaxf(val, 1e-6f), 1.f - 1e-6f);
                out[b * NCAP + t] = val;
            }
        }
    }
}

// ---------------------------------------------------------------------------
extern "C" void kernel_launch(void* const* d_in, const int* in_sizes, int n_in,
                              void* d_out, int out_size, void* d_ws, size_t ws_size,
                              hipStream_t stream) {
    const float* x    = (const float*)d_in[0];
    const float* W    = (const float*)d_in[1];
    const float* bias = (const float*)d_in[2];
    const float* l1w  = (const float*)d_in[3];
    const float* l1b  = (const float*)d_in[4];
    const float* l2w  = (const float*)d_in[5];
    const float* l2b  = (const float*)d_in[6];
    float* out = (float*)d_out;            // [256,128]; doubles as a1/gate scratch
    float* p   = out + B_SZ * NCAP;        // [256,128,128,32]

    hipMemsetAsync(out, 0, B_SZ * NCAP * sizeof(float), stream);
    gemm1_kernel<<<dim3(2, 4, 96), 256, 0, stream>>>(x, l1w, out);
    att_kernel<<<dim3(B_SZ), 128, 0, stream>>>(out, l1b, l2w, l2b);

    const size_t xh_elems = (size_t)B_SZ * NCAP * D_INP;   // 25165824
    const size_t wh_elems = (size_t)NO * D_INP;            // 3145728
    if (ws_size >= (xh_elems + wh_elems) * sizeof(_Float16)) {
        _Float16* xh = (_Float16*)d_ws;
        _Float16* wh = xh + xh_elems;
        convert_kernel<<<dim3((int)(xh_elems / 8 / 256)), 256, 0, stream>>>(x, xh);
        convert_kernel<<<dim3((int)(wh_elems / 8 / 256)), 256, 0, stream>>>(W, wh);
        gemm2_mfma<<<dim3(32, B_SZ), 256, 0, stream>>>(xh, wh, bias, out, p);
    } else {
        gemm2_kernel<<<dim3(32, B_SZ), 256, 0, stream>>>(x, W, bias, out, p);
    }
    routing_kernel<<<dim3(B_SZ), 512, 0, stream>>>(p, out);
}